// Round 1
// baseline (274.878 us; speedup 1.0000x reference)
//
#include <hip/hip_runtime.h>
#include <math.h>

// Problem constants (fixed by the reference setup_inputs)
#define NIMG   64
#define CDIM   64
#define HWPX   4096
#define KCL    128
#define PARTS  8            // blocks per image
#define PIXPART (HWPX / PARTS)   // 512 pixels per block
#define TL     32           // pixels per chunk
#define NCHUNK (PIXPART / TL)    // 16

// ---------------------------------------------------------------------------
// Kernel 1: fused  normalize -> 1x1 conv (logits) -> softmax -> VLAD partial
// grid = NIMG*PARTS blocks of 256 threads; each block handles 512 pixels of
// one image and atomically accumulates vacc[n][k][c] and asum[n][k].
// ---------------------------------------------------------------------------
__global__ __launch_bounds__(256, 2)
void netvlad_main(const float* __restrict__ x,       // [N][C][HW]
                  const float* __restrict__ conv_w,  // [K][C]
                  const float* __restrict__ conv_b,  // [K]
                  float* __restrict__ vacc_g,        // [N][K][C] (pre-zeroed)
                  float* __restrict__ asum_g)        // [N][K]    (pre-zeroed)
{
    __shared__ float cw[CDIM][KCL];   // conv_w transposed: cw[c][k]   32 KB
    __shared__ float cb[KCL];
    __shared__ float xt[CDIM][36];    // raw x tile xt[c][p] (+pad)     9 KB
    __shared__ float sa[TL][132];     // sa[p][k]: logits->exp->probs  16.5 KB
    __shared__ float red[TL][9];      // per-pixel partial reductions
    __shared__ float prn[TL];         // 1 / max(||x||,eps)
    __shared__ float pn[TL];          // max(||x||,eps)
    __shared__ float pm[TL];          // softmax max
    __shared__ float pscale[TL];      // (1/sumExp) * prn

    const int t    = threadIdx.x;
    const int n    = blockIdx.x >> 3;
    const int part = blockIdx.x & 7;

    // Stage conv_w (transposed) and bias once per block
    #pragma unroll
    for (int i = 0; i < 32; ++i) {
        int e = t + i * 256;            // 8192 elems
        cw[e & 63][e >> 6] = conv_w[e];
    }
    if (t < KCL) cb[t] = conv_b[t];

    // thread roles
    const int p_ld = t & 31, cb8 = t >> 5;     // loader: pixel, c-block
    const int k0a = (t & 31) * 4;              // mm1: 4 k's
    const int p0a = (t >> 5) * 4;              // mm1: 4 pixels
    const int pp  = t >> 3, pt = t & 7;        // softmax: pixel, k-part
    const int ks  = pt * 16;
    const int k0b = (t & 15) * 8;              // mm2: 8 k's
    const int c0b = (t >> 4) * 4;              // mm2: 4 c's

    float vacc[8][4];
    #pragma unroll
    for (int a = 0; a < 8; ++a)
        #pragma unroll
        for (int b = 0; b < 4; ++b) vacc[a][b] = 0.f;
    float asum_reg = 0.f;

    const float* xbase = x + (size_t)n * CDIM * HWPX + part * PIXPART;

    for (int ch = 0; ch < NCHUNK; ++ch) {
        const int l0 = ch * TL;
        __syncthreads();                       // xt/sa free from prev chunk

        // ---- load x tile + per-pixel sum of squares -----------------------
        float ssq = 0.f;
        #pragma unroll
        for (int j = 0; j < 8; ++j) {
            int c = cb8 * 8 + j;
            float v = xbase[(size_t)c * HWPX + l0 + p_ld];
            xt[c][p_ld] = v;
            ssq += v * v;
        }
        red[p_ld][cb8] = ssq;
        __syncthreads();
        if (t < TL) {
            float s = 0.f;
            #pragma unroll
            for (int j = 0; j < 8; ++j) s += red[t][j];
            float nrm = fmaxf(sqrtf(s), 1e-12f);   // torch F.normalize eps
            pn[t]  = nrm;
            prn[t] = 1.0f / nrm;
        }
        __syncthreads();

        // ---- matmul1: logits[p][k] = (sum_c w[k,c]*x[c,p]) * rn[p] + b[k] -
        float a1[4][4];
        #pragma unroll
        for (int a = 0; a < 4; ++a)
            #pragma unroll
            for (int b = 0; b < 4; ++b) a1[a][b] = 0.f;
        #pragma unroll 4
        for (int c = 0; c < CDIM; ++c) {
            const float4 w  = *(const float4*)&cw[c][k0a];
            const float4 xv = *(const float4*)&xt[c][p0a];
            const float wk[4] = {w.x, w.y, w.z, w.w};
            const float xp[4] = {xv.x, xv.y, xv.z, xv.w};
            #pragma unroll
            for (int jp = 0; jp < 4; ++jp)
                #pragma unroll
                for (int jk = 0; jk < 4; ++jk)
                    a1[jp][jk] = fmaf(wk[jk], xp[jp], a1[jp][jk]);
        }
        {
            const float4 cbv = *(const float4*)&cb[k0a];
            #pragma unroll
            for (int jp = 0; jp < 4; ++jp) {
                const float s = prn[p0a + jp];
                float4 o;
                o.x = fmaf(a1[jp][0], s, cbv.x);
                o.y = fmaf(a1[jp][1], s, cbv.y);
                o.z = fmaf(a1[jp][2], s, cbv.z);
                o.w = fmaf(a1[jp][3], s, cbv.w);
                *(float4*)&sa[p0a + jp][k0a] = o;
            }
        }
        __syncthreads();

        // ---- softmax over k (128) per pixel -------------------------------
        float m = -3.4e38f;
        #pragma unroll
        for (int q = 0; q < 4; ++q) {
            float4 v = *(const float4*)&sa[pp][ks + 4 * q];
            m = fmaxf(m, fmaxf(fmaxf(v.x, v.y), fmaxf(v.z, v.w)));
        }
        red[pp][pt] = m;
        __syncthreads();
        if (t < TL) {
            float mm = red[t][0];
            #pragma unroll
            for (int j = 1; j < 8; ++j) mm = fmaxf(mm, red[t][j]);
            pm[t] = mm;
        }
        __syncthreads();

        float es = 0.f;
        {
            const float mp = pm[pp];
            #pragma unroll
            for (int q = 0; q < 4; ++q) {
                float4 v = *(const float4*)&sa[pp][ks + 4 * q];
                v.x = __expf(v.x - mp);
                v.y = __expf(v.y - mp);
                v.z = __expf(v.z - mp);
                v.w = __expf(v.w - mp);
                es += (v.x + v.y) + (v.z + v.w);
                *(float4*)&sa[pp][ks + 4 * q] = v;
            }
        }
        red[pp][pt] = es;
        __syncthreads();
        if (t < TL) {
            float s = 0.f;
            #pragma unroll
            for (int j = 0; j < 8; ++j) s += red[t][j];
            pscale[t] = (1.0f / s) * prn[t];   // fold 1/||x|| into probs
        }
        __syncthreads();

        // scale exp -> prob * rn  (so mm2 directly produces sum sa*xn)
        {
            const float sc = pscale[pp];
            #pragma unroll
            for (int q = 0; q < 4; ++q) {
                float4 v = *(const float4*)&sa[pp][ks + 4 * q];
                v.x *= sc; v.y *= sc; v.z *= sc; v.w *= sc;
                *(float4*)&sa[pp][ks + 4 * q] = v;
            }
        }
        __syncthreads();

        // ---- matmul2: vacc[k][c] += sum_p sa_scaled[p][k] * xraw[c][p] ----
        #pragma unroll 2
        for (int p = 0; p < TL; ++p) {
            const float4 s0 = *(const float4*)&sa[p][k0b];
            const float4 s1 = *(const float4*)&sa[p][k0b + 4];
            const float sk[8] = {s0.x, s0.y, s0.z, s0.w, s1.x, s1.y, s1.z, s1.w};
            float xc[4];
            #pragma unroll
            for (int j = 0; j < 4; ++j) xc[j] = xt[c0b + j][p];
            #pragma unroll
            for (int jk = 0; jk < 8; ++jk)
                #pragma unroll
                for (int jc = 0; jc < 4; ++jc)
                    vacc[jk][jc] = fmaf(sk[jk], xc[jc], vacc[jk][jc]);
        }
        // asum[k] = sum_p prob[k,p]; sa_scaled*pn == exp*inv (rn*nrm == 1)
        if (t < KCL) {
            #pragma unroll 4
            for (int p = 0; p < TL; ++p)
                asum_reg += sa[p][t] * pn[p];
        }
    }

    // ---- combine block partials ------------------------------------------
    float* vg = vacc_g + (size_t)n * KCL * CDIM;
    #pragma unroll
    for (int jk = 0; jk < 8; ++jk)
        #pragma unroll
        for (int jc = 0; jc < 4; ++jc)
            atomicAdd(&vg[(k0b + jk) * CDIM + c0b + jc], vacc[jk][jc]);
    if (t < KCL) atomicAdd(&asum_g[n * KCL + t], asum_reg);
}

// ---------------------------------------------------------------------------
// Kernel 2: vlad = vacc - asum*centroids; intra-norm per k; global L2 norm.
// One block per image, 256 threads: thread t handles (k = t/2, 32 c's).
// ---------------------------------------------------------------------------
__global__ __launch_bounds__(256)
void netvlad_finalize(const float* __restrict__ vacc_g,
                      const float* __restrict__ asum_g,
                      const float* __restrict__ cent,   // [K][C]
                      float* __restrict__ out)          // [N][K*C]
{
    __shared__ float wred[4];
    __shared__ float gsh;

    const int t = threadIdx.x;
    const int n = blockIdx.x;
    const int k = t >> 1, half = t & 1, c0 = half * 32;

    const float* vg = vacc_g + (size_t)n * KCL * CDIM + k * CDIM + c0;
    const float* cg = cent + k * CDIM + c0;
    const float  av = asum_g[n * KCL + k];

    float raw[32];
    float ss = 0.f;
    #pragma unroll
    for (int q = 0; q < 8; ++q) {
        float4 v = *(const float4*)&vg[4 * q];
        float4 c = *(const float4*)&cg[4 * q];
        float r0 = v.x - av * c.x;
        float r1 = v.y - av * c.y;
        float r2 = v.z - av * c.z;
        float r3 = v.w - av * c.w;
        raw[4 * q + 0] = r0; raw[4 * q + 1] = r1;
        raw[4 * q + 2] = r2; raw[4 * q + 3] = r3;
        ss += r0 * r0 + r1 * r1 + r2 * r2 + r3 * r3;
    }
    ss += __shfl_xor(ss, 1);                       // full row sumsq (64 c)
    const float rinv = 1.0f / fmaxf(sqrtf(ss), 1e-12f);

    // global sumsq after intra-norm: sum_k ss_k * rinv_k^2 (count once/row)
    float contrib = (half == 0) ? ss * rinv * rinv : 0.f;
    #pragma unroll
    for (int off = 1; off < 64; off <<= 1) contrib += __shfl_xor(contrib, off);
    if ((t & 63) == 0) wred[t >> 6] = contrib;
    __syncthreads();
    if (t == 0) {
        float g = wred[0] + wred[1] + wred[2] + wred[3];
        gsh = 1.0f / fmaxf(sqrtf(g), 1e-12f);
    }
    __syncthreads();

    const float s = rinv * gsh;
    float* og = out + (size_t)n * KCL * CDIM + k * CDIM + c0;
    #pragma unroll
    for (int q = 0; q < 8; ++q) {
        float4 o;
        o.x = raw[4 * q + 0] * s;
        o.y = raw[4 * q + 1] * s;
        o.z = raw[4 * q + 2] * s;
        o.w = raw[4 * q + 3] * s;
        *(float4*)&og[4 * q] = o;
    }
}

// ---------------------------------------------------------------------------
extern "C" void kernel_launch(void* const* d_in, const int* in_sizes, int n_in,
                              void* d_out, int out_size, void* d_ws, size_t ws_size,
                              hipStream_t stream) {
    const float* x     = (const float*)d_in[0];   // [64,64,64,64]
    const float* cent  = (const float*)d_in[1];   // [128,64]
    const float* convw = (const float*)d_in[2];   // [128,64]
    const float* convb = (const float*)d_in[3];   // [128]
    float* out  = (float*)d_out;

    float* vacc = (float*)d_ws;                           // [N][K][C]
    float* asum = vacc + (size_t)NIMG * KCL * CDIM;       // [N][K]
    const size_t zbytes = ((size_t)NIMG * KCL * CDIM + (size_t)NIMG * KCL) * sizeof(float);
    hipMemsetAsync(d_ws, 0, zbytes, stream);

    netvlad_main<<<dim3(NIMG * PARTS), dim3(256), 0, stream>>>(x, convw, convb, vacc, asum);
    netvlad_finalize<<<dim3(NIMG), dim3(256), 0, stream>>>(vacc, asum, cent, out);
}

// Round 2
// 157.346 us; speedup vs baseline: 1.7470x; 1.7470x over previous
//
#include <hip/hip_runtime.h>
#include <math.h>

// Problem constants (fixed by the reference setup_inputs)
#define NIMG   64
#define CDIM   64
#define HWPX   4096
#define KCL    128
#define PARTS  8
#define PIXPART (HWPX / PARTS)   // 512 pixels per block
#define TL     32                // pixels per chunk
#define NCHUNK (PIXPART / TL)    // 16

// LDS strides (dwords). XPC_S/XCL_S/PHL_S are multiples of 4 so b128
// (int4) accesses stay 16B-aligned; LG_S=33 breaks power-of-2 conflicts.
#define XPC_S  68
#define XCL_S  36
#define LG_S   33
#define PHL_S  36

typedef __attribute__((ext_vector_type(8))) short short8; // 8 bf16 (4 VGPR)
typedef __attribute__((ext_vector_type(4))) float f32x4;  // MFMA C/D

// round-to-nearest-even float -> bf16 (values are finite here)
__device__ __forceinline__ unsigned f2bf(float f) {
    unsigned u = __builtin_bit_cast(unsigned, f);
    return (u + 0x7fffu + ((u >> 16) & 1u)) >> 16;
}
__device__ __forceinline__ float bf2f(unsigned h) {
    return __builtin_bit_cast(float, h << 16);
}
// pack hi|lo split of f into one dword: low16 = bf16(f), high16 = bf16(f - hi)
__device__ __forceinline__ unsigned packsplit(float f) {
    unsigned hi = f2bf(f);
    float lo = f - bf2f(hi);
    return hi | (f2bf(lo) << 16);
}
__device__ __forceinline__ void unpack8(int4 a, int4 b, short8& h, short8& l) {
    int d[8] = {a.x, a.y, a.z, a.w, b.x, b.y, b.z, b.w};
    #pragma unroll
    for (int j = 0; j < 8; ++j) {
        h[j] = (short)(d[j] & 0xffff);
        l[j] = (short)(((unsigned)d[j]) >> 16);
    }
}

#define MFMA(a, b, c) __builtin_amdgcn_mfma_f32_16x16x32_bf16((a), (b), (c), 0, 0, 0)

// ---------------------------------------------------------------------------
// Kernel 1 (MFMA): normalize -> logits (W@Xn) -> softmax -> V += P@Xn^T
// grid = NIMG*PARTS blocks, 256 threads (4 waves). Wave w owns k-cluster
// tiles {2w, 2w+1}. Split-bf16 (3 MFMA terms) for fp32-grade accuracy.
// ---------------------------------------------------------------------------
__global__ __launch_bounds__(256, 2)
void netvlad_main(const float* __restrict__ x,       // [N][C][HW]
                  const float* __restrict__ conv_w,  // [K][C]
                  const float* __restrict__ conv_b,  // [K]
                  float* __restrict__ vout,          // partials or atomic acc
                  float* __restrict__ asout,
                  int use_atomic)
{
    __shared__ __align__(16) unsigned xpc[TL * XPC_S];   // xn hi|lo, [p][c]
    __shared__ __align__(16) unsigned xcl[CDIM * XCL_S]; // xn hi|lo, [c][p]
    __shared__ __align__(16) float    lg[KCL * LG_S];    // logits [k][p]
    __shared__ __align__(16) unsigned phl[KCL * PHL_S];  // P hi|lo  [k][p]
    __shared__ float redA[TL][9];
    __shared__ float redB[TL][9];
    __shared__ float cb[KCL];

    const int t    = threadIdx.x;
    const int w    = t >> 6;            // wave id 0..3
    const int l    = t & 63;            // lane
    const int l15  = l & 15, l4 = l >> 4;
    const int n    = blockIdx.x >> 3;
    const int part = blockIdx.x & 7;
    const int p    = t & 31;            // staging/softmax pixel
    const int sg   = t >> 5;            // staging c-group / softmax k-segment

    if (t < KCL) cb[t] = conv_b[t];

    // ---- W A-fragments in registers (once per block) ----------------------
    // A[m=kcl][k=c]: lane holds row 16*(2w+kt)+l15, c = 32*ks + 8*l4 + j
    short8 wh[2][2], wl[2][2];
    #pragma unroll
    for (int kt = 0; kt < 2; ++kt) {
        const int krow = (2 * w + kt) * 16 + l15;
        #pragma unroll
        for (int ks = 0; ks < 2; ++ks) {
            const float* wp = conv_w + krow * CDIM + ks * 32 + l4 * 8;
            #pragma unroll
            for (int j = 0; j < 8; ++j) {
                float v = wp[j];
                unsigned hi = f2bf(v);
                wh[kt][ks][j] = (short)hi;
                wl[kt][ks][j] = (short)f2bf(v - bf2f(hi));
            }
        }
    }

    f32x4 acc2[2][4];                   // V tiles: [ktile][ctile]
    #pragma unroll
    for (int a = 0; a < 2; ++a)
        #pragma unroll
        for (int b = 0; b < 4; ++b) acc2[a][b] = (f32x4)0.0f;
    float asr[16];                      // per-(pixel,seg) P sums
    #pragma unroll
    for (int j = 0; j < 16; ++j) asr[j] = 0.f;

    const float* xbase = x + (size_t)n * CDIM * HWPX + part * PIXPART;

    for (int ch = 0; ch < NCHUNK; ++ch) {
        __syncthreads();                                    // bar A

        // ---- stage x chunk: 64c x 32p; thread = (p, c-group sg) ----------
        float xv[8], ssq = 0.f;
        #pragma unroll
        for (int j = 0; j < 8; ++j) {
            xv[j] = xbase[(size_t)(sg * 8 + j) * HWPX + ch * TL + p];
            ssq += xv[j] * xv[j];
        }
        redA[p][sg] = ssq;
        __syncthreads();                                    // bar B
        float s = 0.f;
        #pragma unroll
        for (int j = 0; j < 8; ++j) s += redA[p][j];
        const float rn = 1.0f / fmaxf(sqrtf(s), 1e-12f);
        {
            unsigned d[8];
            #pragma unroll
            for (int j = 0; j < 8; ++j) {
                d[j] = packsplit(xv[j] * rn);
                xcl[(sg * 8 + j) * XCL_S + p] = d[j];
            }
            int4* dst = (int4*)&xpc[p * XPC_S + sg * 8];
            dst[0] = make_int4(d[0], d[1], d[2], d[3]);
            dst[1] = make_int4(d[4], d[5], d[6], d[7]);
        }
        __syncthreads();                                    // bar C

        // ---- mm1: logits[kcl][p] = W @ Xn  (K = c = 64, 2 ksteps) --------
        f32x4 a1[2][2];
        #pragma unroll
        for (int a = 0; a < 2; ++a)
            #pragma unroll
            for (int b = 0; b < 2; ++b) a1[a][b] = (f32x4)0.0f;
        #pragma unroll
        for (int ks = 0; ks < 2; ++ks) {
            #pragma unroll
            for (int pt = 0; pt < 2; ++pt) {
                const int4* bp = (const int4*)&xpc[(pt * 16 + l15) * XPC_S + ks * 32 + l4 * 8];
                short8 bh, bl;
                unpack8(bp[0], bp[1], bh, bl);
                #pragma unroll
                for (int kt = 0; kt < 2; ++kt) {
                    a1[kt][pt] = MFMA(wh[kt][ks], bh, a1[kt][pt]);
                    a1[kt][pt] = MFMA(wh[kt][ks], bl, a1[kt][pt]);
                    a1[kt][pt] = MFMA(wl[kt][ks], bh, a1[kt][pt]);
                }
            }
        }
        #pragma unroll
        for (int kt = 0; kt < 2; ++kt)
            #pragma unroll
            for (int pt = 0; pt < 2; ++pt)
                #pragma unroll
                for (int i = 0; i < 4; ++i) {
                    const int row = (2 * w + kt) * 16 + l4 * 4 + i;
                    lg[row * LG_S + pt * 16 + l15] = a1[kt][pt][i] + cb[row];
                }
        __syncthreads();                                    // bar D

        // ---- softmax over kcl per pixel; thread = (p, 16-k segment sg) ---
        float v[16];
        #pragma unroll
        for (int j = 0; j < 16; ++j) v[j] = lg[(sg * 16 + j) * LG_S + p];
        float m = v[0];
        #pragma unroll
        for (int j = 1; j < 16; ++j) m = fmaxf(m, v[j]);
        redA[p][sg] = m;
        __syncthreads();                                    // bar E
        #pragma unroll
        for (int j = 0; j < 8; ++j) m = fmaxf(m, redA[p][j]);
        float es = 0.f;
        #pragma unroll
        for (int j = 0; j < 16; ++j) { v[j] = __expf(v[j] - m); es += v[j]; }
        redB[p][sg] = es;
        __syncthreads();                                    // bar F
        float sum = 0.f;
        #pragma unroll
        for (int j = 0; j < 8; ++j) sum += redB[p][j];
        const float sc = 1.0f / sum;
        #pragma unroll
        for (int j = 0; j < 16; ++j) {
            const float P = v[j] * sc;
            asr[j] += P;
            phl[(sg * 16 + j) * PHL_S + p] = packsplit(P);
        }
        __syncthreads();                                    // bar G

        // ---- mm2: V[kcl][c] += P @ Xn^T  (K = l = 32, 1 kstep) -----------
        short8 xh2[4], xl2[4];
        #pragma unroll
        for (int ct = 0; ct < 4; ++ct) {
            const int4* bp = (const int4*)&xcl[(ct * 16 + l15) * XCL_S + l4 * 8];
            unpack8(bp[0], bp[1], xh2[ct], xl2[ct]);
        }
        #pragma unroll
        for (int kt = 0; kt < 2; ++kt) {
            const int4* ap = (const int4*)&phl[((2 * w + kt) * 16 + l15) * PHL_S + l4 * 8];
            short8 ah, al;
            unpack8(ap[0], ap[1], ah, al);
            #pragma unroll
            for (int ct = 0; ct < 4; ++ct) {
                acc2[kt][ct] = MFMA(ah, xh2[ct], acc2[kt][ct]);
                acc2[kt][ct] = MFMA(ah, xl2[ct], acc2[kt][ct]);
                acc2[kt][ct] = MFMA(al, xh2[ct], acc2[kt][ct]);
            }
        }
    }

    // ---- write V partial (or atomic-accumulate) --------------------------
    float* vg = use_atomic ? vout + (size_t)n * KCL * CDIM
                           : vout + (size_t)(n * PARTS + part) * KCL * CDIM;
    #pragma unroll
    for (int kt = 0; kt < 2; ++kt)
        #pragma unroll
        for (int ct = 0; ct < 4; ++ct)
            #pragma unroll
            for (int i = 0; i < 4; ++i) {
                const int row = (2 * w + kt) * 16 + l4 * 4 + i;
                const int col = ct * 16 + l15;
                if (use_atomic) atomicAdd(&vg[row * CDIM + col], acc2[kt][ct][i]);
                else            vg[row * CDIM + col] = acc2[kt][ct][i];
            }

    // ---- asum: dump per-thread partials into lg, reduce over 32 pixels ---
    __syncthreads();
    #pragma unroll
    for (int j = 0; j < 16; ++j) lg[(sg * 16 + j) * LG_S + p] = asr[j];
    __syncthreads();
    if (t < KCL) {
        float s = 0.f;
        #pragma unroll 8
        for (int pp = 0; pp < TL; ++pp) s += lg[t * LG_S + pp];
        if (use_atomic) atomicAdd(&asout[n * KCL + t], s);
        else            asout[(n * PARTS + part) * KCL + t] = s;
    }
}

// ---------------------------------------------------------------------------
// Kernel 2: sum partials; vlad = V - asum*centroids; intra-norm; global norm.
// One block per image; thread t -> (k = t/2, 32 c's).
// ---------------------------------------------------------------------------
__global__ __launch_bounds__(256)
void netvlad_finalize(const float* __restrict__ vpart,   // [N][nparts][K][C]
                      const float* __restrict__ aspart,  // [N][nparts][K]
                      const float* __restrict__ cent,    // [K][C]
                      float* __restrict__ out,           // [N][K*C]
                      int nparts)
{
    __shared__ float wred[4];
    __shared__ float gsh;

    const int t = threadIdx.x;
    const int n = blockIdx.x;
    const int k = t >> 1, half = t & 1, c0 = half * 32;

    float vsum[32];
    #pragma unroll
    for (int j = 0; j < 32; ++j) vsum[j] = 0.f;
    float av = 0.f;
    for (int pt = 0; pt < nparts; ++pt) {
        const float* vg = vpart + (((size_t)n * nparts + pt) * KCL + k) * CDIM + c0;
        #pragma unroll
        for (int g = 0; g < 8; ++g) {
            float4 vq = *(const float4*)&vg[4 * g];
            vsum[4 * g + 0] += vq.x; vsum[4 * g + 1] += vq.y;
            vsum[4 * g + 2] += vq.z; vsum[4 * g + 3] += vq.w;
        }
        av += aspart[(n * nparts + pt) * KCL + k];
    }

    const float* cg = cent + k * CDIM + c0;
    float ss = 0.f;
    #pragma unroll
    for (int g = 0; g < 8; ++g) {
        float4 cq = *(const float4*)&cg[4 * g];
        float r0 = vsum[4 * g + 0] - av * cq.x;
        float r1 = vsum[4 * g + 1] - av * cq.y;
        float r2 = vsum[4 * g + 2] - av * cq.z;
        float r3 = vsum[4 * g + 3] - av * cq.w;
        vsum[4 * g + 0] = r0; vsum[4 * g + 1] = r1;
        vsum[4 * g + 2] = r2; vsum[4 * g + 3] = r3;
        ss += r0 * r0 + r1 * r1 + r2 * r2 + r3 * r3;
    }
    ss += __shfl_xor(ss, 1);                     // full-row sumsq (64 c)
    const float rinv = 1.0f / fmaxf(sqrtf(ss), 1e-12f);

    float contrib = (half == 0) ? ss * rinv * rinv : 0.f;
    #pragma unroll
    for (int off = 1; off < 64; off <<= 1) contrib += __shfl_xor(contrib, off);
    if ((t & 63) == 0) wred[t >> 6] = contrib;
    __syncthreads();
    if (t == 0) {
        float g = wred[0] + wred[1] + wred[2] + wred[3];
        gsh = 1.0f / fmaxf(sqrtf(g), 1e-12f);
    }
    __syncthreads();

    const float sfin = rinv * gsh;
    float* og = out + (size_t)n * KCL * CDIM + k * CDIM + c0;
    #pragma unroll
    for (int g = 0; g < 8; ++g) {
        float4 o;
        o.x = vsum[4 * g + 0] * sfin;
        o.y = vsum[4 * g + 1] * sfin;
        o.z = vsum[4 * g + 2] * sfin;
        o.w = vsum[4 * g + 3] * sfin;
        *(float4*)&og[4 * g] = o;
    }
}

// ---------------------------------------------------------------------------
extern "C" void kernel_launch(void* const* d_in, const int* in_sizes, int n_in,
                              void* d_out, int out_size, void* d_ws, size_t ws_size,
                              hipStream_t stream) {
    const float* x     = (const float*)d_in[0];   // [64,64,64,64]
    const float* cent  = (const float*)d_in[1];   // [128,64]
    const float* convw = (const float*)d_in[2];   // [128,64]
    const float* convb = (const float*)d_in[3];   // [128]
    float* out = (float*)d_out;

    const size_t need8 = (size_t)NIMG * PARTS * (KCL * CDIM + KCL) * sizeof(float);
    int nparts, use_atomic;
    if (ws_size >= need8) { nparts = PARTS; use_atomic = 0; }
    else                  { nparts = 1;     use_atomic = 1; }

    float* vws  = (float*)d_ws;                               // [N][nparts][K][C]
    float* asws = vws + (size_t)NIMG * nparts * KCL * CDIM;   // [N][nparts][K]
    if (use_atomic) {
        const size_t zb = (size_t)NIMG * (KCL * CDIM + KCL) * sizeof(float);
        hipMemsetAsync(d_ws, 0, zb, stream);
    }

    netvlad_main<<<dim3(NIMG * PARTS), dim3(256), 0, stream>>>(x, convw, convb, vws, asws, use_atomic);
    netvlad_finalize<<<dim3(NIMG), dim3(256), 0, stream>>>(vws, asws, cent, out, nparts);
}